// Round 1
// baseline (43.802 us; speedup 1.0000x reference)
//
#include <hip/hip_runtime.h>

#define BB 16384
#define DD 1024
// 256 threads/block, 4 float4 elems per thread covers D=1024 exactly.

__global__ __launch_bounds__(256) void cross_compress_kernel(
    const float* __restrict__ enc_user,
    const float* __restrict__ enc_item,
    const float* __restrict__ t_vv,
    const float* __restrict__ t_ev,
    const float* __restrict__ t_ve,
    const float* __restrict__ t_ee,
    const float* __restrict__ b_v,
    const float* __restrict__ b_e,
    float* __restrict__ out)   // [0:B*D) = v_out, [B*D:2*B*D) = e_out
{
    const int row  = blockIdx.x;
    const int tid  = threadIdx.x;
    const int c    = tid << 2;                 // column of this thread's float4
    const long base = (long)row * DD;

    const float4 u  = *reinterpret_cast<const float4*>(enc_user + base + c);
    const float4 it = *reinterpret_cast<const float4*>(enc_item + base + c);
    const float4 vv = *reinterpret_cast<const float4*>(t_vv + c);
    const float4 ev = *reinterpret_cast<const float4*>(t_ev + c);
    const float4 ve = *reinterpret_cast<const float4*>(t_ve + c);
    const float4 ee = *reinterpret_cast<const float4*>(t_ee + c);

    // Partial dot products (per reference):
    //   e_vv = enc_item . t_vv ; v_ev = enc_user . t_ev
    //   e_ve = enc_item . t_ve ; v_ee = enc_user . t_ee
    float s0 = it.x*vv.x + it.y*vv.y + it.z*vv.z + it.w*vv.w;  // e_vv
    float s1 =  u.x*ev.x +  u.y*ev.y +  u.z*ev.z +  u.w*ev.w;  // v_ev
    float s2 = it.x*ve.x + it.y*ve.y + it.z*ve.z + it.w*ve.w;  // e_ve
    float s3 =  u.x*ee.x +  u.y*ee.y +  u.z*ee.z +  u.w*ee.w;  // v_ee

    // 64-lane butterfly reduce within each wave
    #pragma unroll
    for (int off = 32; off > 0; off >>= 1) {
        s0 += __shfl_xor(s0, off);
        s1 += __shfl_xor(s1, off);
        s2 += __shfl_xor(s2, off);
        s3 += __shfl_xor(s3, off);
    }

    // Cross-wave combine: 4 waves x 4 sums in LDS, broadcast read back.
    __shared__ float red[4][4];
    const int wave = tid >> 6;
    if ((tid & 63) == 0) {
        red[wave][0] = s0; red[wave][1] = s1;
        red[wave][2] = s2; red[wave][3] = s3;
    }
    __syncthreads();

    const float e_vv = red[0][0] + red[1][0] + red[2][0] + red[3][0];
    const float v_ev = red[0][1] + red[1][1] + red[2][1] + red[3][1];
    const float e_ve = red[0][2] + red[1][2] + red[2][2] + red[3][2];
    const float v_ee = red[0][3] + red[1][3] + red[2][3] + red[3][3];

    const float4 bv = *reinterpret_cast<const float4*>(b_v + c);
    const float4 be = *reinterpret_cast<const float4*>(b_e + c);

    float4 vo, eo;
    vo.x = u.x*e_vv + it.x*v_ev + bv.x;
    vo.y = u.y*e_vv + it.y*v_ev + bv.y;
    vo.z = u.z*e_vv + it.z*v_ev + bv.z;
    vo.w = u.w*e_vv + it.w*v_ev + bv.w;

    eo.x = u.x*e_ve + it.x*v_ee + be.x;
    eo.y = u.y*e_ve + it.y*v_ee + be.y;
    eo.z = u.z*e_ve + it.z*v_ee + be.z;
    eo.w = u.w*e_ve + it.w*v_ee + be.w;

    *reinterpret_cast<float4*>(out + base + c)                     = vo;
    *reinterpret_cast<float4*>(out + (long)BB * DD + base + c)     = eo;
}

extern "C" void kernel_launch(void* const* d_in, const int* in_sizes, int n_in,
                              void* d_out, int out_size, void* d_ws, size_t ws_size,
                              hipStream_t stream) {
    const float* enc_user = (const float*)d_in[0];
    const float* enc_item = (const float*)d_in[1];
    const float* t_vv     = (const float*)d_in[2];
    const float* t_ev     = (const float*)d_in[3];
    const float* t_ve     = (const float*)d_in[4];
    const float* t_ee     = (const float*)d_in[5];
    const float* b_v      = (const float*)d_in[6];
    const float* b_e      = (const float*)d_in[7];
    float* out = (float*)d_out;

    dim3 grid(BB);
    dim3 block(256);
    cross_compress_kernel<<<grid, block, 0, stream>>>(
        enc_user, enc_item, t_vv, t_ev, t_ve, t_ee, b_v, b_e, out);
}

// Round 3
// 43.422 us; speedup vs baseline: 1.0087x; 1.0087x over previous
//
#include <hip/hip_runtime.h>

#define BB 16384
#define DD 1024
// 256 threads/block, 1 float4 per thread covers D=1024 exactly.
// Outputs are streamed with nontemporal stores so the 256 MiB L3 retains the
// 128 MiB of encoder inputs across graph replays (R1 showed L3 held ~50% of
// inputs with regular stores; nt stores should push input FETCH toward 0).

typedef float f32x4 __attribute__((ext_vector_type(4)));

__global__ __launch_bounds__(256) void cross_compress_kernel(
    const float* __restrict__ enc_user,
    const float* __restrict__ enc_item,
    const float* __restrict__ t_vv,
    const float* __restrict__ t_ev,
    const float* __restrict__ t_ve,
    const float* __restrict__ t_ee,
    const float* __restrict__ b_v,
    const float* __restrict__ b_e,
    float* __restrict__ out)   // [0:B*D) = v_out, [B*D:2*B*D) = e_out
{
    const int row  = blockIdx.x;
    const int tid  = threadIdx.x;
    const int c    = tid << 2;                 // column of this thread's float4
    const long base = (long)row * DD;

    const f32x4 u  = *reinterpret_cast<const f32x4*>(enc_user + base + c);
    const f32x4 it = *reinterpret_cast<const f32x4*>(enc_item + base + c);
    const f32x4 vv = *reinterpret_cast<const f32x4*>(t_vv + c);
    const f32x4 ev = *reinterpret_cast<const f32x4*>(t_ev + c);
    const f32x4 ve = *reinterpret_cast<const f32x4*>(t_ve + c);
    const f32x4 ee = *reinterpret_cast<const f32x4*>(t_ee + c);

    // Partial dot products (per reference):
    //   e_vv = enc_item . t_vv ; v_ev = enc_user . t_ev
    //   e_ve = enc_item . t_ve ; v_ee = enc_user . t_ee
    float s0 = it.x*vv.x + it.y*vv.y + it.z*vv.z + it.w*vv.w;  // e_vv
    float s1 =  u.x*ev.x +  u.y*ev.y +  u.z*ev.z +  u.w*ev.w;  // v_ev
    float s2 = it.x*ve.x + it.y*ve.y + it.z*ve.z + it.w*ve.w;  // e_ve
    float s3 =  u.x*ee.x +  u.y*ee.y +  u.z*ee.z +  u.w*ee.w;  // v_ee

    // 64-lane butterfly reduce within each wave
    #pragma unroll
    for (int off = 32; off > 0; off >>= 1) {
        s0 += __shfl_xor(s0, off);
        s1 += __shfl_xor(s1, off);
        s2 += __shfl_xor(s2, off);
        s3 += __shfl_xor(s3, off);
    }

    // Cross-wave combine: 4 waves x 4 sums in LDS, broadcast read back.
    __shared__ float red[4][4];
    const int wave = tid >> 6;
    if ((tid & 63) == 0) {
        red[wave][0] = s0; red[wave][1] = s1;
        red[wave][2] = s2; red[wave][3] = s3;
    }
    __syncthreads();

    const float e_vv = red[0][0] + red[1][0] + red[2][0] + red[3][0];
    const float v_ev = red[0][1] + red[1][1] + red[2][1] + red[3][1];
    const float e_ve = red[0][2] + red[1][2] + red[2][2] + red[3][2];
    const float v_ee = red[0][3] + red[1][3] + red[2][3] + red[3][3];

    const f32x4 bv = *reinterpret_cast<const f32x4*>(b_v + c);
    const f32x4 be = *reinterpret_cast<const f32x4*>(b_e + c);

    f32x4 vo, eo;
    vo.x = u.x*e_vv + it.x*v_ev + bv.x;
    vo.y = u.y*e_vv + it.y*v_ev + bv.y;
    vo.z = u.z*e_vv + it.z*v_ev + bv.z;
    vo.w = u.w*e_vv + it.w*v_ev + bv.w;

    eo.x = u.x*e_ve + it.x*v_ee + be.x;
    eo.y = u.y*e_ve + it.y*v_ee + be.y;
    eo.z = u.z*e_ve + it.z*v_ee + be.z;
    eo.w = u.w*e_ve + it.w*v_ee + be.w;

    // Nontemporal streaming stores: outputs are never re-read by the kernel.
    __builtin_nontemporal_store(vo, reinterpret_cast<f32x4*>(out + base + c));
    __builtin_nontemporal_store(eo, reinterpret_cast<f32x4*>(out + (long)BB * DD + base + c));
}

extern "C" void kernel_launch(void* const* d_in, const int* in_sizes, int n_in,
                              void* d_out, int out_size, void* d_ws, size_t ws_size,
                              hipStream_t stream) {
    const float* enc_user = (const float*)d_in[0];
    const float* enc_item = (const float*)d_in[1];
    const float* t_vv     = (const float*)d_in[2];
    const float* t_ev     = (const float*)d_in[3];
    const float* t_ve     = (const float*)d_in[4];
    const float* t_ee     = (const float*)d_in[5];
    const float* b_v      = (const float*)d_in[6];
    const float* b_e      = (const float*)d_in[7];
    float* out = (float*)d_out;

    dim3 grid(BB);
    dim3 block(256);
    cross_compress_kernel<<<grid, block, 0, stream>>>(
        enc_user, enc_item, t_vv, t_ev, t_ve, t_ee, b_v, b_e, out);
}